// Round 7
// baseline (1619.173 us; speedup 1.0000x reference)
//
#include <hip/hip_runtime.h>
#include <hip/hip_bf16.h>

#define SEQ  200
#define DIM  512
#define NH   8
#define DF   64
#define SPAD 256
#define NEG  -1.0e30f

typedef __bf16 bf16x8 __attribute__((ext_vector_type(8)));
typedef float  f32x4  __attribute__((ext_vector_type(4)));

// ---------------------------------------------------------------------------
// Per-tensor dtype detection (512 u16 words). flag=1 -> f32.
// ---------------------------------------------------------------------------
__global__ void detect_kernel(const unsigned short* __restrict__ src,
                              int* __restrict__ flag)
{
    __shared__ int cnt;
    if (threadIdx.x == 0) cnt = 0;
    __syncthreads();
    int ok = 0;
#pragma unroll
    for (int i = 0; i < 2; ++i) {
        const unsigned short u = src[threadIdx.x * 2 + i];
        const float f = __uint_as_float(((unsigned int)u) << 16);
        const float a = fabsf(f);
        ok += (f == 0.0f) || (a >= 6.0e-5f && a <= 64.0f);
    }
    atomicAdd(&cnt, ok);
    __syncthreads();
    if (threadIdx.x == 0) flag[0] = (cnt < 448) ? 1 : 0;
}

// ---------------------------------------------------------------------------
// Canonicalize a tensor to bf16 according to its own flag.
// ---------------------------------------------------------------------------
__global__ void cvt_kernel(const void* __restrict__ src,
                           __bf16* __restrict__ dst, long n8,
                           const int* __restrict__ flag)
{
    const int f32mode = flag[0];
    long i = (long)blockIdx.x * blockDim.x + threadIdx.x;
    const long stride = (long)gridDim.x * blockDim.x;
    if (f32mode) {
        const f32x4* s = (const f32x4*)src;
        for (; i < n8; i += stride) {
            const f32x4 a = s[2 * i], b = s[2 * i + 1];
            bf16x8 o;
            o[0] = (__bf16)a[0]; o[1] = (__bf16)a[1];
            o[2] = (__bf16)a[2]; o[3] = (__bf16)a[3];
            o[4] = (__bf16)b[0]; o[5] = (__bf16)b[1];
            o[6] = (__bf16)b[2]; o[7] = (__bf16)b[3];
            ((bf16x8*)dst)[i] = o;
        }
    } else {
        const bf16x8* s = (const bf16x8*)src;
        for (; i < n8; i += stride) ((bf16x8*)dst)[i] = s[i];
    }
}

// ---------------------------------------------------------------------------
// GEMM: C = A[m_off.., K] @ Bt[N,K]^T + bias[N]; fp32 accum.
// A dtype per-tensor via flag when USE_FLAG (f32 converted during staging).
// OutT = __bf16 for intermediates, float for the final output (d_out is the
// reference's f32 output buffer!).
// MODE 0: C row-major [M,N]; MODE 1: C->[b,H,S,DF]; MODE 2: C->[b,H,DF,SPAD].
// ---------------------------------------------------------------------------
template <int MODE, int USE_FLAG, typename OutT>
__global__ __launch_bounds__(256, 2)
void gemm_bt_kernel(const void* __restrict__ Araw, long m_off,
                    const __bf16* __restrict__ Bt,
                    const __bf16* __restrict__ bias,
                    OutT* __restrict__ C,
                    int M, int N, int K,
                    const int* __restrict__ flag)
{
    __shared__ __align__(16) __bf16 lA[128 * 32];
    __shared__ __align__(16) __bf16 lB[128 * 32];

    const int af32 = USE_FLAG ? flag[0] : 0;
    const __bf16* A16 = (const __bf16*)Araw;
    const float*  A32 = (const float*)Araw;

    const int tid  = threadIdx.x;
    const int m0   = blockIdx.x * 128;
    const int n0   = blockIdx.y * 128;
    const int w    = tid >> 6;
    const int lane = tid & 63;
    const int lr   = lane & 15, quad = lane >> 4;
    const int wm   = (w >> 1) * 64, wn = (w & 1) * 64;

    f32x4 acc[4][4] = {};

    for (int k0 = 0; k0 < K; k0 += 32) {
        bf16x8 ra[2]; uint4 rb[2];
#pragma unroll
        for (int p = 0; p < 2; ++p) {
            const int e = (p * 256 + tid) * 8;
            const int row = e >> 5, col = e & 31;
            const size_t aoff = (size_t)(m_off + m0 + row) * K + (k0 + col);
            if (af32) {
                const f32x4 fa = *(const f32x4*)(A32 + aoff);
                const f32x4 fb = *(const f32x4*)(A32 + aoff + 4);
                bf16x8 o;
                o[0] = (__bf16)fa[0]; o[1] = (__bf16)fa[1];
                o[2] = (__bf16)fa[2]; o[3] = (__bf16)fa[3];
                o[4] = (__bf16)fb[0]; o[5] = (__bf16)fb[1];
                o[6] = (__bf16)fb[2]; o[7] = (__bf16)fb[3];
                ra[p] = o;
            } else {
                ra[p] = *(const bf16x8*)(A16 + aoff);
            }
            rb[p] = *(const uint4*)(Bt + (size_t)(n0 + row) * K + (k0 + col));
        }
        __syncthreads();
#pragma unroll
        for (int p = 0; p < 2; ++p) {
            const int e = (p * 256 + tid) * 8;
            *(bf16x8*)&lA[e] = ra[p];
            *(uint4*)&lB[e]  = rb[p];
        }
        __syncthreads();

        bf16x8 af[4], bfr[4];
#pragma unroll
        for (int mi = 0; mi < 4; ++mi)
            af[mi] = *(const bf16x8*)&lA[(wm + mi * 16 + lr) * 32 + quad * 8];
#pragma unroll
        for (int ni = 0; ni < 4; ++ni)
            bfr[ni] = *(const bf16x8*)&lB[(wn + ni * 16 + lr) * 32 + quad * 8];
#pragma unroll
        for (int mi = 0; mi < 4; ++mi)
#pragma unroll
            for (int ni = 0; ni < 4; ++ni)
                acc[mi][ni] = __builtin_amdgcn_mfma_f32_16x16x32_bf16(
                    af[mi], bfr[ni], acc[mi][ni], 0, 0, 0);
    }

    // C/D layout: col=lane&15, row=quad*4+r  [diag1-verified on-device]
#pragma unroll
    for (int ni = 0; ni < 4; ++ni) {
        const int col = n0 + wn + ni * 16 + lr;
        const float bb = (float)bias[col];
#pragma unroll
        for (int mi = 0; mi < 4; ++mi) {
#pragma unroll
            for (int r = 0; r < 4; ++r) {
                const int row = m0 + wm + mi * 16 + quad * 4 + r;
                const float vv = acc[mi][ni][r] + bb;
                size_t addr;
                if (MODE == 0) {
                    addr = (size_t)row * N + col;
                } else {
                    const int b = row / SEQ, s = row - b * SEQ;
                    const int h = col >> 6, df = col & 63;
                    if (MODE == 1)
                        addr = (((size_t)(b * NH + h)) * SEQ + s) * DF + df;
                    else
                        addr = (((size_t)(b * NH + h)) * DF + df) * SPAD + s;
                }
                C[addr] = (OutT)vv;
            }
        }
    }
}

// ---------------------------------------------------------------------------
// Naive attention (kept this round: one variable at a time). One block per
// (b,h); K/V staged in LDS once; per-q scalar scores, block softmax, PV.
// ---------------------------------------------------------------------------
__device__ __forceinline__ float wave_max(float x) {
#pragma unroll
    for (int o = 1; o < 64; o <<= 1) x = fmaxf(x, __shfl_xor(x, o, 64));
    return x;
}
__device__ __forceinline__ float wave_sum(float x) {
#pragma unroll
    for (int o = 1; o < 64; o <<= 1) x += __shfl_xor(x, o, 64);
    return x;
}

__global__ __launch_bounds__(256)
void attn_naive(const __bf16* __restrict__ Qh,
                const __bf16* __restrict__ Kh,
                const __bf16* __restrict__ Vt,
                __bf16* __restrict__ Ctx,
                const int* __restrict__ zp)
{
    __shared__ __bf16 Kl[SEQ * DF];
    __shared__ __bf16 Vl[DF * SEQ];
    __shared__ float  qv[DF];
    __shared__ float  pbuf[256];
    __shared__ float  comb[256];
    __shared__ float  rmax[4], rsum[4];

    const int tid = threadIdx.x;
    const int bh  = blockIdx.x;
    const int b   = bh >> 3, h = bh & 7;
    const size_t qkbase = (size_t)bh * SEQ * DF;
    const size_t vbase  = (size_t)bh * DF * SPAD;
    const int w = tid >> 6, lane = tid & 63;
    const int zero_pad = zp[0];

    for (int i = tid; i < SEQ * DF / 8; i += 256)
        ((bf16x8*)Kl)[i] = *(const bf16x8*)(Kh + qkbase + (size_t)i * 8);
    for (int i = tid; i < DF * (SEQ / 8); i += 256) {
        const int d = i / (SEQ / 8), blk = i % (SEQ / 8);
        *(bf16x8*)&Vl[d * SEQ + blk * 8] =
            *(const bf16x8*)(Vt + vbase + (size_t)d * SPAD + blk * 8);
    }
    __syncthreads();

    for (int q = 0; q < SEQ; ++q) {
        if (tid < DF) qv[tid] = (float)Qh[qkbase + (size_t)q * DF + tid];
        __syncthreads();

        float s = NEG;
        if (tid <= q && tid < SEQ) {
            float a = 0.0f;
#pragma unroll 8
            for (int d = 0; d < DF; ++d)
                a += (float)Kl[tid * DF + d] * qv[d];
            s = a * 0.125f;
        }
        const float wmx = wave_max(s);
        if (lane == 0) rmax[w] = wmx;
        __syncthreads();
        const float m = fmaxf(fmaxf(rmax[0], rmax[1]), fmaxf(rmax[2], rmax[3]));
        const float pr = __expf(s - m);
        pbuf[tid] = pr;
        const float wsm = wave_sum(pr);
        if (lane == 0) rsum[w] = wsm;
        __syncthreads();
        const float l = rsum[0] + rsum[1] + rsum[2] + rsum[3];

        const int d = tid & 63, part = tid >> 6;
        float a = 0.0f;
        for (int j = part * 50; j < part * 50 + 50; ++j)
            a += pbuf[j] * (float)Vl[d * SEQ + j];
        comb[tid] = a;
        __syncthreads();

        if (tid < DF) {
            const float tot = comb[tid] + comb[tid + 64] + comb[tid + 128] + comb[tid + 192];
            const bool zr = (zero_pad != 0) && (q == 0);
            const float ov = zr ? 0.0f : tot / l;
            Ctx[((size_t)(b * SEQ + q)) * DIM + h * DF + tid] = (__bf16)ov;
        }
        __syncthreads();
    }
}

// ---------------------------------------------------------------------------
extern "C" void kernel_launch(void* const* d_in, const int* in_sizes, int n_in,
                              void* d_out, int out_size, void* d_ws, size_t ws_size,
                              hipStream_t stream)
{
    const void* q  = d_in[0];
    const void* k  = d_in[1];
    const void* v  = d_in[2];
    const void* Ws[4] = {d_in[3], d_in[5], d_in[7], d_in[9]};
    const void* bs[4] = {d_in[4], d_in[6], d_in[8], d_in[10]};
    const int*  zp = (const int*)d_in[12];
    float* Out = (float*)d_out;          // reference output dtype is FLOAT32

    // flags at ints [0..10]
    int* flags = (int*)d_ws;
    __bf16* Wc[4]; __bf16* bc[4];
    __bf16* p = (__bf16*)((char*)d_ws + 256);
    for (int i = 0; i < 4; ++i) { Wc[i] = p; p += (size_t)DIM * DIM; }
    for (int i = 0; i < 4; ++i) { bc[i] = p; p += DIM; }
    const size_t fixed_bytes = (size_t)((char*)p - (char*)d_ws);

    const int B_total = 128;
    int cb = 128;
    while (cb > 16) {
        const size_t crows_t = (size_t)cb * SEQ;
        const size_t elems = 3 * crows_t * DIM + (size_t)cb * NH * DF * SPAD;
        if (fixed_bytes + elems * 2 <= ws_size) break;
        cb >>= 1;
    }
    const int nchunk = B_total / cb;
    const size_t crows = (size_t)cb * SEQ;
    const size_t celems = crows * DIM;

    __bf16* Qh  = p;
    __bf16* Kh  = Qh + celems;
    __bf16* Vt  = Kh + celems;                       // [cb,H,DF,SPAD]
    __bf16* Ctx = Vt + (size_t)cb * NH * DF * SPAD;  // [crows, DIM]

    const dim3 blk(256);
    const dim3 g((unsigned)(crows / 128), DIM / 128);

    // per-tensor dtype detection (inputs may be bf16-ified by the harness)
    detect_kernel<<<1, 256, 0, stream>>>((const unsigned short*)q, &flags[0]);
    detect_kernel<<<1, 256, 0, stream>>>((const unsigned short*)k, &flags[1]);
    detect_kernel<<<1, 256, 0, stream>>>((const unsigned short*)v, &flags[2]);
    for (int i = 0; i < 4; ++i) {
        detect_kernel<<<1, 256, 0, stream>>>((const unsigned short*)Ws[i], &flags[3 + i]);
        detect_kernel<<<1, 256, 0, stream>>>((const unsigned short*)bs[i], &flags[7 + i]);
    }
    for (int i = 0; i < 4; ++i) {
        cvt_kernel<<<128, 256, 0, stream>>>(Ws[i], Wc[i], (long)DIM * DIM / 8, &flags[3 + i]);
        cvt_kernel<<<1, 64, 0, stream>>>(bs[i], bc[i], DIM / 8, &flags[7 + i]);
    }

    for (int c = 0; c < nchunk; ++c) {
        const long moff = (long)c * (long)crows;
        gemm_bt_kernel<1, 1, __bf16><<<g, blk, 0, stream>>>(
            q, moff, Wc[0], bc[0], Qh, (int)crows, DIM, DIM, &flags[0]);
        gemm_bt_kernel<1, 1, __bf16><<<g, blk, 0, stream>>>(
            k, moff, Wc[1], bc[1], Kh, (int)crows, DIM, DIM, &flags[1]);
        gemm_bt_kernel<2, 1, __bf16><<<g, blk, 0, stream>>>(
            v, moff, Wc[2], bc[2], Vt, (int)crows, DIM, DIM, &flags[2]);
        attn_naive<<<dim3(cb * NH), blk, 0, stream>>>(Qh, Kh, Vt, Ctx, zp);
        gemm_bt_kernel<0, 0, float><<<g, blk, 0, stream>>>(
            Ctx, 0, Wc[3], bc[3], Out + (size_t)c * celems,
            (int)crows, DIM, DIM, nullptr);
    }
}